// Round 5
// baseline (1315.625 us; speedup 1.0000x reference)
//
#include <hip/hip_runtime.h>
#include <math.h>

// StressCapsuleLayer: capsule dynamic routing (3 iters), fused recompute design.
//   x [128][648][16] f32, W [648][32][32][16] f32 -> v [128][32][32] f32
//
// 3 passes over (b,n); u_hat recomputed each pass (never materialized).
//   pass0: c = 1/32 exactly            -> s0 -> v0 = squash(s0)
//   pass1: logit = <u_hat, v0>         -> softmax_j -> s1 -> v1
//   pass2: logit = <u,v0> + <u,v1>     -> softmax_j -> s2 -> v2 = output
//
// R5 changes (GLDS-write experiment + L2 fix):
//  1. NO global_load_lds anywhere. All four prior rounds showed WRITE_SIZE ~=
//     2 x staged-bytes + stores (fits within 1% in every round), independent of
//     source-address pattern -> gfx950 LDS-DMA return path is counted/routed
//     as 32B TCC WRITES per 16B lane request. Staging is now reg-staged:
//     coalesced global_load_dwordx4 -> XOR-swizzled ds_write_b128.
//     Swizzle p = c ^ ((c>>6)&7): write = 2 lanes/bank-group/phase (free),
//     read = contiguous 256B per 16-lane phase (zero conflict).
//  2. B_CH=32 (512-thread blocks, 8 waves x 4 b): only 4 b-chunks -> per-XCD
//     W working set 9 slices x 6 n x 64KB = 3.5MB < 4MB L2, sharers
//     co-resident -> W read from HBM ~once per pass (FETCH 430 -> ~60-90MB).
//  3. Next-tile W prefetched into staging regs before compute (latency hidden
//     under the 2048-cyc FMA phase). launch_bounds(512,2): no forced spill.

#define N_IN 648
#define ELEMS 131072      // 128*32*32 output elements

template <int PHASE>
__global__ __launch_bounds__(512, 2) void caps_pass(
    const float* __restrict__ x,     // [128][648][16]
    const float* __restrict__ W,     // [648][32][32][16]
    const float* __restrict__ v0,    // [128][32][32]  (PHASE>=1)
    const float* __restrict__ v1,    // [128][32][32]  (PHASE==2)
    float* __restrict__ parts,       // [NC][128][32][32] disjoint partial sums
    int NC, int nPer)                // n-chunks, n's per block (648 / NC)
{
  // 64KB. W[n]-quad (jj,d,iq) lives at LDS quad p = c ^ ((c>>6)&7),
  // c = ((d&15)*4+iq)*64 + (d>>4)*32 + jj.
  __shared__ float4 wlds[4096];

  const int t = threadIdx.x;
  const int w = t >> 6;   // wave 0..7
  const int l = t & 63;   // lane
  const int j = l & 31;
  const int dblk = l >> 5;

  // XCD-aware decode: bid&7 = XCD (round-robin dispatch). Each XCD owns a
  // contiguous n-chunk slice; consecutive rem -> same n-slice, different
  // b-chunk, so the 4 blocks sharing W[n] are co-resident on one XCD's L2.
  int nchunk, bchunk;
  {
    const int bid = blockIdx.x;
    if ((NC & 7) == 0) {
      const int ng = NC >> 3;          // n-chunks per XCD
      const int xcd = bid & 7;
      const int rem = bid >> 3;        // 0 .. NC/2-1
      bchunk = rem & 3;                // fastest: b-chunk (W reuse in L2)
      nchunk = xcd * ng + (rem >> 2);
    } else {
      nchunk = bid % NC;
      bchunk = bid / NC;
    }
  }
  const int n0 = nchunk * nPer;
  const int b0 = bchunk * 32;

  // per-thread read offsets: quad for (k,iq) at byte kq*1024 + offv[kq&7],
  // offv[m] = dblk*512 + 16*(j^m)
  int offv[8];
#pragma unroll
  for (int m = 0; m < 8; ++m) offv[m] = dblk * 512 + 16 * (j ^ m);

  // per-thread staging targets: quad g = r*512 + t -> LDS byte addr
  int stb[8];
#pragma unroll
  for (int r = 0; r < 8; ++r) {
    const int g = r * 512 + t;
    const int jj = g >> 7;
    const int d = (g >> 2) & 31;
    const int iq = g & 3;
    const int c = ((d & 15) * 4 + iq) * 64 + (d >> 4) * 32 + jj;
    stb[r] = 16 * (c ^ ((c >> 6) & 7));
  }

  float s_acc[4][16];
#pragma unroll
  for (int bb = 0; bb < 4; ++bb)
#pragma unroll
    for (int k = 0; k < 16; ++k) s_acc[bb][k] = 0.f;

  // prologue: load tile 0 into staging regs (coalesced: 1KB/wave/round)
  float4 st[8];
  {
    const float4* Wn = (const float4*)(W + (size_t)n0 * 16384);
#pragma unroll
    for (int r = 0; r < 8; ++r) st[r] = Wn[r * 512 + t];
  }

  for (int nn = 0; nn < nPer; ++nn) {
    const int n = n0 + nn;

    __syncthreads();  // previous tile's LDS reads complete
#pragma unroll
    for (int r = 0; r < 8; ++r)
      *(float4*)((char*)wlds + stb[r]) = st[r];
    __syncthreads();  // writes visible

    // prefetch next tile (regs free after ds_write consumed them at issue);
    // HBM/L2 latency hides under the FMA phase below
    if (nn + 1 < nPer) {
      const float4* Wn = (const float4*)(W + (size_t)(n + 1) * 16384);
#pragma unroll
      for (int r = 0; r < 8; ++r) st[r] = Wn[r * 512 + t];
    }

#pragma unroll
    for (int bbp = 0; bbp < 2; ++bbp) {
      const int b0w = b0 + w * 4 + bbp * 2;
      const float4* xp0 = (const float4*)(x + ((size_t)(b0w + 0) * N_IN + n) * 16);
      const float4* xp1 = (const float4*)(x + ((size_t)(b0w + 1) * N_IN + n) * 16);

      float u[2][16];
#pragma unroll
      for (int k = 0; k < 16; ++k) { u[0][k] = 0.f; u[1][k] = 0.f; }

#pragma unroll
      for (int iq = 0; iq < 4; ++iq) {
        const float4 xv0 = xp0[iq];  // broadcast load (all lanes same addr)
        const float4 xv1 = xp1[iq];
#pragma unroll
        for (int k = 0; k < 16; ++k) {
          const int kq = k * 4 + iq;
          const float4 wq = *(const float4*)(
              (const char*)wlds + offv[kq & 7] + kq * 1024);
          u[0][k] = fmaf(wq.x, xv0.x, u[0][k]);
          u[0][k] = fmaf(wq.y, xv0.y, u[0][k]);
          u[0][k] = fmaf(wq.z, xv0.z, u[0][k]);
          u[0][k] = fmaf(wq.w, xv0.w, u[0][k]);
          u[1][k] = fmaf(wq.x, xv1.x, u[1][k]);
          u[1][k] = fmaf(wq.y, xv1.y, u[1][k]);
          u[1][k] = fmaf(wq.z, xv1.z, u[1][k]);
          u[1][k] = fmaf(wq.w, xv1.w, u[1][k]);
        }
      }

#pragma unroll
      for (int h = 0; h < 2; ++h) {
        const int bb = bbp * 2 + h;
        const int b = b0w + h;
        float c;
        if (PHASE == 0) {
          c = 1.0f / 32.0f;  // softmax(zeros) exactly
        } else {
          float logit = 0.f;
          {
            const float4* vp = (const float4*)(v0 + (size_t)b * 1024 + j * 32 + dblk * 16);
            float a = 0.f;
#pragma unroll
            for (int q = 0; q < 4; ++q) {
              const float4 vv = vp[q];
              a = fmaf(u[h][q * 4 + 0], vv.x, a);
              a = fmaf(u[h][q * 4 + 1], vv.y, a);
              a = fmaf(u[h][q * 4 + 2], vv.z, a);
              a = fmaf(u[h][q * 4 + 3], vv.w, a);
            }
            logit += a;
          }
          if (PHASE == 2) {
            const float4* vp = (const float4*)(v1 + (size_t)b * 1024 + j * 32 + dblk * 16);
            float a = 0.f;
#pragma unroll
            for (int q = 0; q < 4; ++q) {
              const float4 vv = vp[q];
              a = fmaf(u[h][q * 4 + 0], vv.x, a);
              a = fmaf(u[h][q * 4 + 1], vv.y, a);
              a = fmaf(u[h][q * 4 + 2], vv.z, a);
              a = fmaf(u[h][q * 4 + 3], vv.w, a);
            }
            logit += a;
          }
          // full agreement over d: combine the two d-halves
          logit += __shfl_xor(logit, 32);
          // softmax over 32 j's (width-32 butterflies; halves are identical)
          float m = logit;
#pragma unroll
          for (int off = 16; off >= 1; off >>= 1) m = fmaxf(m, __shfl_xor(m, off));
          const float e = __expf(logit - m);
          float Z = e;
#pragma unroll
          for (int off = 16; off >= 1; off >>= 1) Z += __shfl_xor(Z, off);
          c = e / Z;
        }
#pragma unroll
        for (int k = 0; k < 16; ++k) s_acc[bb][k] = fmaf(c, u[h][k], s_acc[bb][k]);
      }
    }
  }

  // disjoint partial store: parts[chunk][b][j][d] -- no atomics, no contention
  float* pbase = parts + (size_t)nchunk * ELEMS;
#pragma unroll
  for (int bb = 0; bb < 4; ++bb) {
    const int b = b0 + w * 4 + bb;
    float* sp = pbase + (size_t)b * 1024 + j * 32 + dblk * 16;
#pragma unroll
    for (int k = 0; k < 16; ++k) sp[k] = s_acc[bb][k];
  }
}

// stage B: sum NC partials, then squash over last dim (32) via width-32 shuffle
__global__ void reduce_squash(const float* __restrict__ parts, int NC,
                              float* __restrict__ v) {
  const int e = blockIdx.x * 256 + threadIdx.x;  // rows of 32 align to half-waves
  float s = 0.f;
  for (int c = 0; c < NC; ++c) s += parts[(size_t)c * ELEMS + e];
  float s2 = s * s;
#pragma unroll
  for (int off = 16; off >= 1; off >>= 1) s2 += __shfl_xor(s2, off);
  const float scale = (s2 / (1.0f + s2)) * rsqrtf(s2 + 1e-7f);
  v[e] = s * scale;
}

extern "C" void kernel_launch(void* const* d_in, const int* in_sizes, int n_in,
                              void* d_out, int out_size, void* d_ws, size_t ws_size,
                              hipStream_t stream) {
  const float* x = (const float*)d_in[0];
  const float* W = (const float*)d_in[1];
  float* out = (float*)d_out;

  float* v0 = (float*)d_ws;            // 131072 f32
  float* v1 = v0 + ELEMS;              // 131072 f32
  float* parts = v1 + ELEMS;           // NC * 131072 f32

  // choose NC (divisor of 648) from available workspace; deterministic since
  // ws_size is fixed. Prefer NC%8==0 (XCD-grouped W locality), largest first.
  int avail = 0;
  if (ws_size / 4 > 2 * (size_t)ELEMS)
    avail = (int)((ws_size / 4 - 2 * (size_t)ELEMS) / ELEMS);
  const int ladder[] = {72, 24, 8, 81, 54, 27, 18, 12, 9, 6, 4, 3, 2, 1};
  int NC = 1;
  for (int i = 0; i < 14; ++i)
    if (ladder[i] <= avail) { NC = ladder[i]; break; }
  const int nPer = N_IN / NC;

  const dim3 grid(NC * 4);   // 4 b-chunks of 32
  const dim3 blk(512);

  caps_pass<0><<<grid, blk, 0, stream>>>(x, W, nullptr, nullptr, parts, NC, nPer);
  reduce_squash<<<512, 256, 0, stream>>>(parts, NC, v0);

  caps_pass<1><<<grid, blk, 0, stream>>>(x, W, v0, nullptr, parts, NC, nPer);
  reduce_squash<<<512, 256, 0, stream>>>(parts, NC, v1);

  caps_pass<2><<<grid, blk, 0, stream>>>(x, W, v0, v1, parts, NC, nPer);
  reduce_squash<<<512, 256, 0, stream>>>(parts, NC, out);
}

// Round 6
// 400.467 us; speedup vs baseline: 3.2852x; 3.2852x over previous
//
#include <hip/hip_runtime.h>
#include <math.h>

// StressCapsuleLayer: capsule dynamic routing (3 iters), fused recompute design.
//   x [128][648][16] f32, W [648][32][32][16] f32 -> v [128][32][32] f32
//
// 3 passes over (b,n); u_hat recomputed each pass (never materialized).
//   pass0: c = 1/32 exactly            -> s0 -> v0 = squash(s0)
//   pass1: logit = <u_hat, v0>         -> softmax_j -> s1 -> v1
//   pass2: logit = <u,v0> + <u,v1>     -> softmax_j -> s2 -> v2 = output
//
// R6 changes (anti-spill restructure):
//  - Residual ~390MB/pass WRITE (post-GLDS-removal) attributed to scratch
//    spill: R5 live set ~170 regs (s_acc 64 + st 32 + u 32 + misc) vs 128
//    allocated; s_acc RMW 2x/n-iter across 1.33M thread-iters ~= 400MB.
//  - Now 2 b's per thread: s_acc[2][16]=32 regs. No register prefetch (tmp[]
//    dies before compute). Peak live ~108 < 128 -> spill impossible.
//  - 8 b-chunks -> grid = NC*8 = 576 blocks @ 512 thr = 2 blocks/CU: TLP
//    hides staging latency instead of the register prefetch.
//  - LDS swizzle unchanged from R5 (verified: write covers all 32 banks per
//    8 lanes; read 2-way-free; conflicts were ~0).

#define N_IN 648
#define ELEMS 131072      // 128*32*32 output elements

template <int PHASE>
__global__ __launch_bounds__(512, 2) void caps_pass(
    const float* __restrict__ x,     // [128][648][16]
    const float* __restrict__ W,     // [648][32][32][16]
    const float* __restrict__ v0,    // [128][32][32]  (PHASE>=1)
    const float* __restrict__ v1,    // [128][32][32]  (PHASE==2)
    float* __restrict__ parts,       // [NC][128][32][32] disjoint partial sums
    int NC, int nPer)                // n-chunks, n's per block (648 / NC)
{
  // 64KB. W[n]-quad (jj,d,iq) lives at LDS quad p = c ^ ((c>>6)&7),
  // c = ((d&15)*4+iq)*64 + (d>>4)*32 + jj.
  __shared__ float4 wlds[4096];

  const int t = threadIdx.x;
  const int w = t >> 6;   // wave 0..7
  const int l = t & 63;   // lane
  const int j = l & 31;
  const int dblk = l >> 5;

  // XCD-aware decode: bid&7 = XCD (round-robin dispatch). Each XCD owns a
  // contiguous n-chunk slice; consecutive rem -> same n-slice, different
  // b-chunk, so the 8 blocks sharing W[n] are co-resident on one XCD's L2.
  int nchunk, bchunk;
  {
    const int bid = blockIdx.x;
    if ((NC & 7) == 0) {
      const int ng = NC >> 3;          // n-chunks per XCD
      const int xcd = bid & 7;
      const int rem = bid >> 3;        // 0 .. NC-1
      bchunk = rem & 7;                // fastest: b-chunk (W reuse in L2)
      nchunk = xcd * ng + (rem >> 3);
    } else {
      nchunk = bid % NC;
      bchunk = bid / NC;
    }
  }
  const int n0 = nchunk * nPer;
  const int b0 = bchunk * 16;
  const int bA = b0 + w * 2;      // this wave's two b's: bA, bA+1

  // per-thread read offsets: quad for kq=(k*4+iq) at byte kq*1024 + offv[kq&7]
  int offv[8];
#pragma unroll
  for (int m = 0; m < 8; ++m) offv[m] = dblk * 512 + 16 * (j ^ m);

  // per-thread staging targets: quad g = r*512 + t -> LDS byte addr
  int stb[8];
#pragma unroll
  for (int r = 0; r < 8; ++r) {
    const int g = r * 512 + t;
    const int jj = g >> 7;
    const int d = (g >> 2) & 31;
    const int iq = g & 3;
    const int c = ((d & 15) * 4 + iq) * 64 + (d >> 4) * 32 + jj;
    stb[r] = 16 * (c ^ ((c >> 6) & 7));
  }

  float s_acc[2][16];
#pragma unroll
  for (int h = 0; h < 2; ++h)
#pragma unroll
    for (int k = 0; k < 16; ++k) s_acc[h][k] = 0.f;

  for (int nn = 0; nn < nPer; ++nn) {
    const int n = n0 + nn;

    __syncthreads();  // previous tile's LDS reads complete
    {
      const float4* Wn = (const float4*)(W + (size_t)n * 16384);
      float4 tmp[8];    // short-lived: dead before compute phase
#pragma unroll
      for (int r = 0; r < 8; ++r) tmp[r] = Wn[r * 512 + t];  // coalesced
#pragma unroll
      for (int r = 0; r < 8; ++r)
        *(float4*)((char*)wlds + stb[r]) = tmp[r];
    }
    __syncthreads();  // writes visible

    const float4* xp0 = (const float4*)(x + ((size_t)(bA + 0) * N_IN + n) * 16);
    const float4* xp1 = (const float4*)(x + ((size_t)(bA + 1) * N_IN + n) * 16);

    float u[2][16];
#pragma unroll
    for (int k = 0; k < 16; ++k) { u[0][k] = 0.f; u[1][k] = 0.f; }

#pragma unroll
    for (int iq = 0; iq < 4; ++iq) {
      const float4 xv0 = xp0[iq];  // wave-uniform address -> scalar load
      const float4 xv1 = xp1[iq];
#pragma unroll
      for (int k = 0; k < 16; ++k) {
        const int kq = k * 4 + iq;
        const float4 wq = *(const float4*)(
            (const char*)wlds + offv[kq & 7] + kq * 1024);
        u[0][k] = fmaf(wq.x, xv0.x, u[0][k]);
        u[0][k] = fmaf(wq.y, xv0.y, u[0][k]);
        u[0][k] = fmaf(wq.z, xv0.z, u[0][k]);
        u[0][k] = fmaf(wq.w, xv0.w, u[0][k]);
        u[1][k] = fmaf(wq.x, xv1.x, u[1][k]);
        u[1][k] = fmaf(wq.y, xv1.y, u[1][k]);
        u[1][k] = fmaf(wq.z, xv1.z, u[1][k]);
        u[1][k] = fmaf(wq.w, xv1.w, u[1][k]);
      }
    }

#pragma unroll
    for (int h = 0; h < 2; ++h) {
      const int b = bA + h;
      float c;
      if (PHASE == 0) {
        c = 1.0f / 32.0f;  // softmax(zeros) exactly
      } else {
        float logit = 0.f;
        {
          const float4* vp = (const float4*)(v0 + (size_t)b * 1024 + j * 32 + dblk * 16);
          float a = 0.f;
#pragma unroll
          for (int q = 0; q < 4; ++q) {
            const float4 vv = vp[q];
            a = fmaf(u[h][q * 4 + 0], vv.x, a);
            a = fmaf(u[h][q * 4 + 1], vv.y, a);
            a = fmaf(u[h][q * 4 + 2], vv.z, a);
            a = fmaf(u[h][q * 4 + 3], vv.w, a);
          }
          logit += a;
        }
        if (PHASE == 2) {
          const float4* vp = (const float4*)(v1 + (size_t)b * 1024 + j * 32 + dblk * 16);
          float a = 0.f;
#pragma unroll
          for (int q = 0; q < 4; ++q) {
            const float4 vv = vp[q];
            a = fmaf(u[h][q * 4 + 0], vv.x, a);
            a = fmaf(u[h][q * 4 + 1], vv.y, a);
            a = fmaf(u[h][q * 4 + 2], vv.z, a);
            a = fmaf(u[h][q * 4 + 3], vv.w, a);
          }
          logit += a;
        }
        // full agreement over d: combine the two d-halves
        logit += __shfl_xor(logit, 32);
        // softmax over 32 j's (width-32 butterflies; halves are identical)
        float m = logit;
#pragma unroll
        for (int off = 16; off >= 1; off >>= 1) m = fmaxf(m, __shfl_xor(m, off));
        const float e = __expf(logit - m);
        float Z = e;
#pragma unroll
        for (int off = 16; off >= 1; off >>= 1) Z += __shfl_xor(Z, off);
        c = e / Z;
      }
#pragma unroll
      for (int k = 0; k < 16; ++k) s_acc[h][k] = fmaf(c, u[h][k], s_acc[h][k]);
    }
  }

  // disjoint partial store: parts[chunk][b][j][d] -- no atomics, no contention
  float* pbase = parts + (size_t)nchunk * ELEMS;
#pragma unroll
  for (int h = 0; h < 2; ++h) {
    const int b = bA + h;
    float* sp = pbase + (size_t)b * 1024 + j * 32 + dblk * 16;
#pragma unroll
    for (int k = 0; k < 16; ++k) sp[k] = s_acc[h][k];
  }
}

// stage B: sum NC partials, then squash over last dim (32) via width-32 shuffle
__global__ void reduce_squash(const float* __restrict__ parts, int NC,
                              float* __restrict__ v) {
  const int e = blockIdx.x * 256 + threadIdx.x;  // rows of 32 align to half-waves
  float s = 0.f;
  for (int c = 0; c < NC; ++c) s += parts[(size_t)c * ELEMS + e];
  float s2 = s * s;
#pragma unroll
  for (int off = 16; off >= 1; off >>= 1) s2 += __shfl_xor(s2, off);
  const float scale = (s2 / (1.0f + s2)) * rsqrtf(s2 + 1e-7f);
  v[e] = s * scale;
}

extern "C" void kernel_launch(void* const* d_in, const int* in_sizes, int n_in,
                              void* d_out, int out_size, void* d_ws, size_t ws_size,
                              hipStream_t stream) {
  const float* x = (const float*)d_in[0];
  const float* W = (const float*)d_in[1];
  float* out = (float*)d_out;

  float* v0 = (float*)d_ws;            // 131072 f32
  float* v1 = v0 + ELEMS;              // 131072 f32
  float* parts = v1 + ELEMS;           // NC * 131072 f32

  // choose NC (divisor of 648) from available workspace; deterministic since
  // ws_size is fixed. Prefer NC%8==0 (XCD-grouped W locality), largest first.
  int avail = 0;
  if (ws_size / 4 > 2 * (size_t)ELEMS)
    avail = (int)((ws_size / 4 - 2 * (size_t)ELEMS) / ELEMS);
  const int ladder[] = {72, 24, 8, 81, 54, 27, 18, 12, 9, 6, 4, 3, 2, 1};
  int NC = 1;
  for (int i = 0; i < 14; ++i)
    if (ladder[i] <= avail) { NC = ladder[i]; break; }
  const int nPer = N_IN / NC;

  const dim3 grid(NC * 8);   // 8 b-chunks of 16
  const dim3 blk(512);

  caps_pass<0><<<grid, blk, 0, stream>>>(x, W, nullptr, nullptr, parts, NC, nPer);
  reduce_squash<<<512, 256, 0, stream>>>(parts, NC, v0);

  caps_pass<1><<<grid, blk, 0, stream>>>(x, W, v0, nullptr, parts, NC, nPer);
  reduce_squash<<<512, 256, 0, stream>>>(parts, NC, v1);

  caps_pass<2><<<grid, blk, 0, stream>>>(x, W, v0, v1, parts, NC, nPer);
  reduce_squash<<<512, 256, 0, stream>>>(parts, NC, out);
}